// Round 8
// baseline (14.295 us; speedup 1.0000x reference)
//
#include <hip/hip_runtime.h>
#include <math.h>

#define NP 64
#define DD 32
#define NTHREADS 1024
#define NB 8            // blocks; each owns 8 output particles
#define NBUK 1024
#define HSZ (NBUK + NBUK/16)   // swizzled histogram storage (pad every 16)

__device__ __forceinline__ float readlane_f(float v, int lane) {
    return __int_as_float(__builtin_amdgcn_readlane(__float_as_int(v), lane));
}

__global__ __launch_bounds__(NTHREADS)
void svgd_kernel(const float* __restrict__ particle,
                 const float* __restrict__ mu,
                 float* __restrict__ out) {
    __shared__ float    sNarr[NP];
    __shared__ float4   jinfo[NP];       // (sj, 1/sj, -qv_j, 0)
    __shared__ float    dist2[NP*NP];    // 16KB
    __shared__ uint2    wmm[16];         // per-wave (min,max) of tri bits
    __shared__ unsigned hist[HSZ];       // 4.25KB swizzled histogram

    const int tid  = threadIdx.x;
    const int lane = tid & 63;
    const int wv   = tid >> 6;
    const int i0   = blockIdx.x * 8;

    // clear swizzled histogram
    hist[tid] = 0u;
    if (tid < HSZ - NBUK) hist[NBUK + tid] = 0u;

    // ---------- P1: rows from global, norms, dist2 ----------
    float4 xq[8];
    #pragma unroll
    for (int k = 0; k < 8; ++k) xq[k] = ((const float4*)particle)[lane*8 + k];
    float xv[DD];
    #pragma unroll
    for (int k = 0; k < 8; ++k) {
        xv[4*k+0] = xq[k].x; xv[4*k+1] = xq[k].y;
        xv[4*k+2] = xq[k].z; xv[4*k+3] = xq[k].w;
    }
    float sj = 0.f;
    #pragma unroll
    for (int d = 0; d < DD; ++d) sj = fmaf(xv[d], xv[d], sj);

    if (wv == 0) {
        sNarr[lane] = sj;
        float mreg = mu[lane & 31];
        float mdot = 0.f;
        #pragma unroll
        for (int d = 0; d < DD; ++d) mdot = fmaf(readlane_f(mreg, d), xv[d], mdot);
        float inv_sj = 1.0f / sj;
        jinfo[lane] = make_float4(sj, inv_sj, -mdot*inv_sj, 0.f);
    }

    unsigned ubr[4];
    unsigned tmn = 0xFFFFFFFFu, tmx = 0u;
    #pragma unroll
    for (int r = 0; r < 4; ++r) {
        int i = wv*4 + r;
        float acc = 0.f;
        #pragma unroll
        for (int d = 0; d < DD; ++d) acc = fmaf(readlane_f(xv[d], i), xv[d], acc);
        float si = readlane_f(sj, i);
        float d2 = si + sj - 2.f*acc;
        dist2[i*64 + lane] = d2;
        unsigned ub = __float_as_uint(d2);
        ubr[r] = ub;
        if (i < lane) {
            tmn = ub < tmn ? ub : tmn;
            tmx = ub > tmx ? ub : tmx;
        }
    }
    #pragma unroll
    for (int m = 32; m >= 1; m >>= 1) {
        unsigned on = (unsigned)__shfl_xor((int)tmn, m, 64);
        unsigned ox = (unsigned)__shfl_xor((int)tmx, m, 64);
        tmn = on < tmn ? on : tmn;
        tmx = ox > tmx ? ox : tmx;
    }
    if (lane == 0) wmm[wv] = make_uint2(tmn, tmx);
    __syncthreads();                     // B1

    // ---------- P2a: combine min/max, histogram own triangle values --------
    unsigned mnv = 0xFFFFFFFFu, mx = 0u;
    #pragma unroll
    for (int k = 0; k < 16; ++k) {
        uint2 wm = wmm[k];
        mnv = wm.x < mnv ? wm.x : mnv;
        mx  = wm.y > mx  ? wm.y : mx;
    }
    int shift = 15;
    unsigned range = (mx >> shift) - (mnv >> shift);
    while (range > (unsigned)(NBUK-1)) {
        ++shift;
        range = (mx >> shift) - (mnv >> shift);
    }
    const unsigned base = mnv >> shift;
    #pragma unroll
    for (int r = 0; r < 4; ++r) {
        int i = wv*4 + r;
        if (i < lane) {
            unsigned b = (ubr[r] >> shift) - base;
            atomicAdd(&hist[b + (b >> 4)], 1u);
        }
    }

    // prefetch P4 operands (independent of histogram) for waves 0..7
    const int jg = lane >> 3;
    const int q  = lane & 7;
    float4 xr[8], xi4, mu4;
    if (wv < 8) {
        #pragma unroll
        for (int jj = 0; jj < 8; ++jj)
            xr[jj] = ((const float4*)particle)[(jj*8 + jg)*8 + q];
        xi4 = ((const float4*)particle)[(i0 + wv)*8 + q];
        mu4 = ((const float4*)mu)[q];
    }
    __syncthreads();                     // B2

    if (wv >= 8) return;                 // no barriers beyond this point

    // ---------- P2b: per-wave redundant scan for ranks 991/992 -------------
    unsigned creg[16];
    #pragma unroll
    for (int c = 0; c < 16; ++c) creg[c] = hist[17*lane + c];
    unsigned tot = 0;
    #pragma unroll
    for (int c = 0; c < 16; ++c) tot += creg[c];
    unsigned inc = tot;
    #pragma unroll
    for (int m = 1; m < 64; m <<= 1) {
        unsigned o = (unsigned)__shfl_up((int)inc, m, 64);
        if (lane >= m) inc += o;
    }
    const unsigned excl = inc - tot;

    unsigned vbits[2];
    #pragma unroll
    for (int rk = 0; rk < 2; ++rk) {
        unsigned target = 991u + (unsigned)rk;
        bool cond = (excl <= target) && (target < inc);
        unsigned long long mask = __ballot(cond);
        int owner = (int)(__ffsll((long long)mask) - 1);
        unsigned cum = excl; int bl = 0; bool done = false;
        #pragma unroll
        for (int c = 0; c < 16; ++c) {
            cum += creg[c];
            if (!done && cum > target) { bl = c; done = true; }
        }
        int bucket = lane*16 + bl;
        int bsel = __shfl(bucket, owner, 64);
        vbits[rk] = (base + (unsigned)bsel) << shift;
    }
    float med   = 0.5f*(__uint_as_float(vbits[0]) + __uint_as_float(vbits[1]));
    float denom = med * (1.0f/4.1588830833596715f) + 1e-6f;   // /ln(64)+eps
    const float invd = 1.0f / denom;

    // ---------- P4: one wave per output particle, barrier-free -------------
    const int i = i0 + wv;
    const float si = sNarr[i];
    float4 w4 = make_float4(0.f,0.f,0.f,0.f);
    float  kacc = 0.f;
    #pragma unroll
    for (int jj = 0; jj < 8; ++jj) {
        int j = jj*8 + jg;
        float4 ji = jinfo[j];
        float d2  = dist2[i*64 + j];
        float K   = __expf(-d2 * invd);
        float u   = d2 - si - ji.x;
        float E   = K * fmaf(fmaf(invd, u, -(float)(DD-1)), ji.y, ji.z);
        float4 x4 = xr[jj];
        w4.x = fmaf(E, x4.x, w4.x);
        w4.y = fmaf(E, x4.y, w4.y);
        w4.z = fmaf(E, x4.z, w4.z);
        w4.w = fmaf(E, x4.w, w4.w);
        kacc += K;
    }
    // reduce across jg (lane bits 3..5) — in-wave, no LDS
    #pragma unroll
    for (int m = 8; m <= 32; m <<= 1) {
        w4.x += __shfl_xor(w4.x, m, 64);
        w4.y += __shfl_xor(w4.y, m, 64);
        w4.z += __shfl_xor(w4.z, m, 64);
        w4.w += __shfl_xor(w4.w, m, 64);
        kacc += __shfl_xor(kacc, m, 64);
    }
    float4 ji_i = jinfo[i];              // .y = 1/si
    float  c2   = 2.f*invd*kacc;
    w4.x += kacc*mu4.x + c2*xi4.x;
    w4.y += kacc*mu4.y + c2*xi4.y;
    w4.z += kacc*mu4.z + c2*xi4.z;
    w4.w += kacc*mu4.w + c2*xi4.w;
    float rdot = xi4.x*w4.x + xi4.y*w4.y + xi4.z*w4.z + xi4.w*w4.w;
    rdot += __shfl_xor(rdot, 1, 64);
    rdot += __shfl_xor(rdot, 2, 64);
    rdot += __shfl_xor(rdot, 4, 64);
    float s3 = (rdot + (float)(DD-1)) * ji_i.y;
    float gx = (w4.x - xi4.x*s3) * (1.f/(float)NP);
    float gy = (w4.y - xi4.y*s3) * (1.f/(float)NP);
    float gz = (w4.z - xi4.z*s3) * (1.f/(float)NP);
    float gw = (w4.w - xi4.w*s3) * (1.f/(float)NP);
    float4 o4;
    o4.x = xi4.x + fminf(fmaxf(0.1f*gx, -1000.f), 1000.f);
    o4.y = xi4.y + fminf(fmaxf(0.1f*gy, -1000.f), 1000.f);
    o4.z = xi4.z + fminf(fmaxf(0.1f*gz, -1000.f), 1000.f);
    o4.w = xi4.w + fminf(fmaxf(0.1f*gw, -1000.f), 1000.f);
    if (lane < 8) ((float4*)out)[i*8 + q] = o4;
}

extern "C" void kernel_launch(void* const* d_in, const int* in_sizes, int n_in,
                              void* d_out, int out_size, void* d_ws, size_t ws_size,
                              hipStream_t stream) {
    const float* particle = (const float*)d_in[0];
    const float* mu       = (const float*)d_in[1];
    float* outp           = (float*)d_out;
    hipLaunchKernelGGL(svgd_kernel, dim3(NB), dim3(NTHREADS), 0, stream,
                       particle, mu, outp);
}